// Round 6
// baseline (483.643 us; speedup 1.0000x reference)
//
#include <hip/hip_runtime.h>

typedef unsigned short u16;
typedef unsigned int u32;
typedef unsigned long long u64;

typedef __attribute__((ext_vector_type(8))) short short8;   // 8 bf16 = 4 VGPRs
typedef __attribute__((ext_vector_type(4))) float floatx4;  // MFMA accumulator

__device__ __forceinline__ float b2f(u16 h) {
  u32 u = ((u32)h) << 16;
  return __builtin_bit_cast(float, u);
}
__device__ __forceinline__ u16 f2b(float f) {
  u32 u = __builtin_bit_cast(u32, f);
  u32 r = 0x7FFFu + ((u >> 16) & 1u);  // RNE
  return (u16)((u + r) >> 16);
}

// async global->LDS, 16B per lane. LDS dest = wave-uniform base + lane*16.
__device__ __forceinline__ void gl_lds16(const void* g, void* l) {
  __builtin_amdgcn_global_load_lds(
      (__attribute__((address_space(1))) void*)(u64)g,
      (__attribute__((address_space(3))) void*)(u32)(u64)l, 16, 0, 0);
}

// raw workgroup barrier WITHOUT the compiler's vmcnt(0) drain, so
// global_load_lds prefetches stay in flight across it.
__device__ __forceinline__ void wg_barrier() {
  asm volatile("" ::: "memory");
  __builtin_amdgcn_s_barrier();
  asm volatile("" ::: "memory");
}

enum { EPI_PHI_BIAS = 0, EPI_BIAS = 1, EPI_NONE = 2, EPI_ZSCALE = 3,
       EPI_BIAS_F32 = 4, EPI_ZBIAS_F32 = 5 };

// C[m,n] = sum_k A[m,k] * B[n,k]  (both bf16, K-contiguous).
// 256x256x64 tile, 8 waves (2M x 4N, 128x64 per wave), double-buffered 128KiB
// LDS. 4-phase-per-K-tile schedule: phase = (M-half mh, k-slice ks) quadrant,
// per phase {ds_read frags; stage issue; barrier; sched_barrier; setprio MFMA
// x16; [vmcnt(N)]; barrier}. Counted vmcnt (T4), never 0 in steady state.
// CRITICAL grouping (round-5 race fix): load sets are grouped by PHASE
// CONSUMPTION, not array order. A-set n covers rows n*64..n*64+63; a wave's
// mh=0 phase reads rows wm*128..wm*128+63 = sets {A0 (wm=0), A2 (wm=1)}.
//   stage6 = {B0,B1,B2,B3,A0,A2}  -- everything ANY wave reads in P0
//   stage2 = {A1,A3}              -- mh=1 rows, read in P1/P3 only
//   vmcnt(2) @ P3-end: <=2 outstanding = next tile's {A1,A3}
//                      => next tile's {B*,A0,A2} landed before P0 reads.
//   vmcnt(6) @ P0-end: <=6 outstanding = next tile's stage6
//                      => current tile's {A1,A3} landed before P1 reads.
//   Each vmcnt is immediately followed by a barrier, so the per-wave vmcnt
//   guarantee extends to all waves' loads (round-3 lesson).
// WAR: stage(t+1) writes buf[(t+1)&1], last ds_read at tile t-1's P2/P3;
// separated by the P3(t-1)-end barrier (waves pass it only after their
// MFMAs consumed the ds_read data).
// LDS layout per buffer: A[256 rows][8 slots of 16B], slot phys = c ^ (row&7)
// (conflict-free ds_read_b128 per quarter-wave); B at +32768, same scheme.
// Block swizzle: XCD-chunked remap, N-tiles of one M-slab adjacent. gridDim.y
// == 4 and (gx*gy)%8==0 for all launches below.
// Split-K: blockIdx.z = kslice*(abmask+1)+batch; abz=bz&abmask, kbase=(bz>>kshift)*K.
// DUAL: bz selects operand set 1 (A2/B2/bias2/C2, no phi) vs set 0 (phi).
template<int EPI, bool TRANS_OUT, bool DUAL>
__global__ __launch_bounds__(512, 2)
void gemm_bt(const u16* __restrict__ Aall, const u16* __restrict__ Ball,
             const float* __restrict__ bias, const float* __restrict__ Zall,
             void* __restrict__ Call,
             int M, int N, int K, int ldA, int ldB, int ldC,
             long sAb, long sBb, long sCb, long sZb, int abmask, int kshift,
             const u16* __restrict__ Aall2, const u16* __restrict__ Ball2,
             const float* __restrict__ bias2, void* __restrict__ Call2)
{
  constexpr int BOFF   = 32768;        // B tile offset within one buffer
  constexpr int STRIDE = 65536;        // one stage buffer (A 32K + B 32K)
  extern __shared__ char smem[];       // 131072 B dynamic

  const int tid  = threadIdx.x;
  const int lane = tid & 63;
  const int wave = tid >> 6;
  const int wm = wave >> 2, wn = wave & 3;   // 2x4 waves, 128x64 each
  const int fl = lane & 15;
  const int q  = lane >> 4;
  const int r4 = q * 4;

  // XCD-chunked block swizzle; consecutive remapped ids iterate the 4 N-tiles
  // of one M-tile.
  const int orig = blockIdx.x + gridDim.x * blockIdx.y;
  const int nwg8 = (gridDim.x * gridDim.y) >> 3;
  const int wsw  = (orig & 7) * nwg8 + (orig >> 3);
  const int bm0 = (wsw >> 2) * 256;          // gridDim.y == 4 in all launches
  const int bn0 = (wsw & 3) * 256;

  const int bz = blockIdx.z;
  const int abz = bz & abmask;
  const int kbase = (bz >> kshift) * K;

  const u16* Asel = Aall; const u16* Bsel = Ball;
  const float* biasSel = bias; void* Csel = Call;
  bool phi_on = true;
  if constexpr (DUAL) {
    if (bz) { Asel = Aall2; Bsel = Ball2; biasSel = bias2; Csel = Call2; phi_on = false; }
  }

  const u16* Ah = Asel + (size_t)abz * sAb + kbase;
  const u16* Bp = Bsel + (size_t)abz * sBb + kbase;

  // ---- staging addresses (global per-lane pre-swizzled; LDS dest linear) ----
  // tile = 256 rows x 8 slots of 16B = 2048 slots; 512 threads x 4 slots.
  // Load set n covers rows n*64..n*64+63.
  const u16* gA[4]; const u16* gB[4]; int sLo[4];
  #pragma unroll
  for (int n = 0; n < 4; ++n) {
    int j = n * 512 + tid;
    int row = j >> 3, pc = j & 7, c = pc ^ (row & 7);
    gA[n] = Ah + (size_t)(bm0 + row) * ldA + c * 8;
    gB[n] = Bp + (size_t)(bn0 + row) * ldB + c * 8;
    sLo[n] = (n * 512 + wave * 64) * 16;
  }

  // ---- fragment LDS byte offsets (within one stage buffer, ks=0) ----
  // read: row = (wm*128|wn*64) + i*16 + fl, slot c = ks*4 + q, phys = c^(row&7)
  // ks=1 toggles bit2 of the slot -> offset ^ 64.
  int aoff[8], boff[4];
  #pragma unroll
  for (int i = 0; i < 8; ++i) {
    int row = wm * 128 + i * 16 + fl;
    aoff[i] = (row * 8 + (q ^ (row & 7))) * 16;
  }
  #pragma unroll
  for (int i = 0; i < 4; ++i) {
    int row = wn * 64 + i * 16 + fl;
    boff[i] = BOFF + (row * 8 + (q ^ (row & 7))) * 16;
  }

  floatx4 zero = {0.f, 0.f, 0.f, 0.f};
  floatx4 acc[8][4];
  #pragma unroll
  for (int i = 0; i < 8; ++i)
    #pragma unroll
    for (int j = 0; j < 4; ++j) acc[i][j] = zero;

  // issue order matters for the vmcnt algebra:
  // stage6 = P0's working set {B0..B3, A0, A2}; stage2 = {A1, A3}.
  auto stage6 = [&](int k0, char* base) {
    #pragma unroll
    for (int n = 0; n < 4; ++n) gl_lds16(gB[n] + k0, base + BOFF + sLo[n]);
    gl_lds16(gA[0] + k0, base + sLo[0]);
    gl_lds16(gA[2] + k0, base + sLo[2]);
  };
  auto stage2 = [&](int k0, char* base) {
    gl_lds16(gA[1] + k0, base + sLo[1]);
    gl_lds16(gA[3] + k0, base + sLo[3]);
  };

  short8 aF[4], bF[4];
  auto rdB = [&](const char* base, int ks) {
    #pragma unroll
    for (int i = 0; i < 4; ++i) bF[i] = *(const short8*)(base + (boff[i] ^ (ks * 64)));
  };
  auto rdA = [&](const char* base, int mh, int ks) {
    #pragma unroll
    for (int i = 0; i < 4; ++i) aF[i] = *(const short8*)(base + (aoff[mh * 4 + i] ^ (ks * 64)));
  };
  auto mma = [&](int mh) {
    __builtin_amdgcn_s_setprio(1);
    #pragma unroll
    for (int i = 0; i < 4; ++i)
      #pragma unroll
      for (int ni = 0; ni < 4; ++ni)
        acc[mh * 4 + i][ni] =
            __builtin_amdgcn_mfma_f32_16x16x32_bf16(aF[i], bF[ni], acc[mh * 4 + i][ni], 0, 0, 0);
    __builtin_amdgcn_s_setprio(0);
  };

  const int NIT = K >> 6;                 // K-tiles of 64 (K = 256..1024)
  stage6(0, smem); stage2(0, smem);
  asm volatile("s_waitcnt vmcnt(2)" ::: "memory");   // tile 0 P0-set landed
  wg_barrier();
  for (int it = 0; it < NIT; ++it) {
    const char* cur = smem + (it & 1) * STRIDE;
    char* nxt = smem + ((it + 1) & 1) * STRIDE;
    const bool pre = (it + 1 < NIT);
    // ---- P0: quadrant (mh0, ks0) — reads {B*, A0|A2} ----
    rdB(cur, 0); rdA(cur, 0, 0);
    if (pre) stage6((it + 1) * 64, nxt);
    wg_barrier();
    __builtin_amdgcn_sched_barrier(0);
    mma(0);
    if (pre) { asm volatile("s_waitcnt vmcnt(6)" ::: "memory"); }  // tile it {A1,A3} landed
    else     { asm volatile("s_waitcnt vmcnt(0)" ::: "memory"); }
    wg_barrier();
    // ---- P1: quadrant (mh1, ks0), bF reused — reads {A1|A3} ----
    rdA(cur, 1, 0);
    if (pre) stage2((it + 1) * 64, nxt);
    wg_barrier();
    __builtin_amdgcn_sched_barrier(0);
    mma(1);
    wg_barrier();
    // ---- P2: quadrant (mh0, ks1) ----
    rdB(cur, 1); rdA(cur, 0, 1);
    wg_barrier();
    __builtin_amdgcn_sched_barrier(0);
    mma(0);
    wg_barrier();
    // ---- P3: quadrant (mh1, ks1) ----
    rdA(cur, 1, 1);
    wg_barrier();
    __builtin_amdgcn_sched_barrier(0);
    mma(1);
    if (pre) { asm volatile("s_waitcnt vmcnt(2)" ::: "memory"); }  // next P0-set landed
    wg_barrier();
  }

  if constexpr (!TRANS_OUT) {
    #pragma unroll
    for (int mi = 0; mi < 8; ++mi) {
      #pragma unroll
      for (int ni = 0; ni < 4; ++ni) {
        int col = bn0 + wn * 64 + ni * 16 + fl;
        #pragma unroll
        for (int r = 0; r < 4; ++r) {
          int row = bm0 + wm * 128 + mi * 16 + r4 + r;
          float vv = acc[mi][ni][r];
          if constexpr (EPI == EPI_PHI_BIAS) {
            vv += biasSel[col];
            if (phi_on) vv = __expf(-0.5f * vv * vv);
          }
          if constexpr (EPI == EPI_BIAS || EPI == EPI_BIAS_F32) vv += biasSel[col];
          if constexpr (EPI == EPI_ZSCALE) vv *= Zall[(size_t)abz * sZb + row];
          if constexpr (EPI == EPI_ZBIAS_F32)
            vv = vv * Zall[(size_t)abz * sZb + row] + biasSel[col];
          if constexpr (EPI == EPI_BIAS_F32 || EPI == EPI_ZBIAS_F32)
            ((float*)Csel)[(size_t)bz * sCb + (size_t)row * ldC + col] = vv;
          else
            ((u16*)Csel)[(size_t)bz * sCb + (size_t)row * ldC + col] = f2b(vv);
        }
      }
    }
  } else {
    // transpose through LDS in two 128-t-row passes, then coalesced 16B
    // stores into [4][N][4096]. sT = [256 d][136 t-pad] u16 = 69632 B.
    __syncthreads();                      // all compute reads done, smem free
    u16* sT = (u16*)smem;
    #pragma unroll
    for (int h = 0; h < 2; ++h) {
      if (wm == h) {
        #pragma unroll
        for (int mi = 0; mi < 8; ++mi) {
          #pragma unroll
          for (int ni = 0; ni < 4; ++ni) {
            int colL = wn * 64 + ni * 16 + fl;
            int row0 = mi * 16 + r4;
            float bcol = biasSel[bn0 + colL];
            ushort4 hh;
            #pragma unroll
            for (int r = 0; r < 4; ++r) {
              float vv = acc[mi][ni][r] + bcol;
              if (phi_on) vv = __expf(-0.5f * vv * vv);
              ((u16*)&hh)[r] = f2b(vv);
            }
            *(ushort4*)(sT + colL * 136 + row0) = hh;
          }
        }
      }
      __syncthreads();
      #pragma unroll
      for (int i = 0; i < 8; ++i) {
        int c = i * 512 + tid;            // 4096 x 16B chunks (256 d x 128 t)
        int dloc = c >> 4, t16 = (c & 15) * 8;
        int4 vv = *(const int4*)(sT + dloc * 136 + t16);
        int gd = bn0 + dloc;
        int gt = bm0 + h * 128 + t16;
        int batch = gt >> 12, tt = gt & 4095;
        *(int4*)((u16*)Csel + ((size_t)batch * N + gd) * 4096 + tt) = vv;
      }
      __syncthreads();
    }
  }
}

__global__ __launch_bounds__(256)
void wconv(const float* __restrict__ w0, const float* __restrict__ w1,
           const float* __restrict__ w2, const float* __restrict__ w3,
           u16* __restrict__ dst) {
  unsigned e = blockIdx.x * 256 + threadIdx.x;
  int mat = e >> 18;
  size_t off = (size_t)(e & 262143) * 4;
  const float* src = mat == 0 ? w0 : mat == 1 ? w1 : mat == 2 ? w2 : w3;
  float4 v = *(const float4*)(src + off);
  ushort4 h;
  h.x = f2b(v.x); h.y = f2b(v.y); h.z = f2b(v.z); h.w = f2b(v.w);
  *(ushort4*)(dst + (size_t)mat * 1048576 + off) = h;
}

// fp32 -> bf16 one-shot conversion of q,k,v (16.78M elems each), 8 elems/thread
__global__ __launch_bounds__(256)
void qkvconv(const float* __restrict__ q, const float* __restrict__ k,
             const float* __restrict__ v, u16* __restrict__ qb,
             u16* __restrict__ kb, u16* __restrict__ vb) {
  size_t e = (size_t)blockIdx.x * 256 + threadIdx.x;
  int which = (int)(e >> 21);            // 2,097,152 threads per tensor
  size_t off = (e & 2097151) * 8;
  const float* src = which == 0 ? q : which == 1 ? k : v;
  u16* dst = which == 0 ? qb : which == 1 ? kb : vb;
  float4 a = *(const float4*)(src + off);
  float4 b = *(const float4*)(src + off + 4);
  ushort4 h0, h1;
  h0.x = f2b(a.x); h0.y = f2b(a.y); h0.z = f2b(a.z); h0.w = f2b(a.w);
  h1.x = f2b(b.x); h1.y = f2b(b.y); h1.z = f2b(b.z); h1.w = f2b(b.w);
  *(ushort4*)(dst + off) = h0;
  *(ushort4*)(dst + off + 4) = h1;
}

// out[i] = round(sum over 4 K-slices of bf16 partials), 4M elems, slice stride 4M
__global__ __launch_bounds__(256)
void reduce4(const u16* __restrict__ P, u16* __restrict__ out) {
  size_t i = ((size_t)blockIdx.x * 256 + threadIdx.x) * 8;
  int4 a = *(const int4*)(P + i);
  int4 b = *(const int4*)(P + i + 4194304);
  int4 c = *(const int4*)(P + i + 8388608);
  int4 d = *(const int4*)(P + i + 12582912);
  const u16* ha = (const u16*)&a; const u16* hb = (const u16*)&b;
  const u16* hc = (const u16*)&c; const u16* hd = (const u16*)&d;
  ushort4 o0, o1;
  #pragma unroll
  for (int j = 0; j < 8; ++j) {
    float s = b2f(ha[j]) + b2f(hb[j]) + b2f(hc[j]) + b2f(hd[j]);
    ((u16*)(j < 4 ? &o0 : &o1))[j & 3] = f2b(s);
  }
  *(ushort4*)(out + i) = o0;
  *(ushort4*)(out + i + 4) = o1;
}

// Ksum[b*1024+d] = sum_t KT[b][d][t]; one wave per (b,d) row
__global__ __launch_bounds__(256)
void ksum_rows(const u16* __restrict__ KT, float* __restrict__ Ksum) {
  int lane = threadIdx.x & 63;
  int row = blockIdx.x * 4 + (threadIdx.x >> 6);
  const u16* p = KT + (size_t)row * 4096;
  float s = 0.f;
  #pragma unroll
  for (int i = 0; i < 8; ++i) {
    int4 d = *(const int4*)(p + i * 512 + lane * 8);
    const u16* h = (const u16*)&d;
    #pragma unroll
    for (int j = 0; j < 8; ++j) s += b2f(h[j]);
  }
  #pragma unroll
  for (int off = 32; off; off >>= 1) s += __shfl_xor(s, off, 64);
  if (lane == 0) Ksum[row] = s;
}

// Z[t] = 1/(Q[t,:]·Ksum[batch,:] + 1e-6); one wave per token
__global__ __launch_bounds__(256)
void zden(const u16* __restrict__ Qb, const float* __restrict__ Ksum,
          float* __restrict__ Z) {
  int lane = threadIdx.x & 63;
  int t = blockIdx.x * 4 + (threadIdx.x >> 6);
  const u16* qp = Qb + (size_t)t * 1024;
  const float* ks = Ksum + (size_t)(t >> 12) * 1024;
  float s = 0.f;
  #pragma unroll
  for (int i = 0; i < 2; ++i) {
    int idx = i * 512 + lane * 8;
    int4 d = *(const int4*)(qp + idx);
    const u16* h = (const u16*)&d;
    float4 k0 = *(const float4*)(ks + idx);
    float4 k1 = *(const float4*)(ks + idx + 4);
    s += b2f(h[0]) * k0.x + b2f(h[1]) * k0.y + b2f(h[2]) * k0.z + b2f(h[3]) * k0.w
       + b2f(h[4]) * k1.x + b2f(h[5]) * k1.y + b2f(h[6]) * k1.z + b2f(h[7]) * k1.w;
  }
  #pragma unroll
  for (int off = 32; off; off >>= 1) s += __shfl_xor(s, off, 64);
  if (lane == 0) Z[t] = 1.0f / (s + 1e-6f);
}

extern "C" void kernel_launch(void* const* d_in, const int* in_sizes, int n_in,
                              void* d_out, int out_size, void* d_ws, size_t ws_size,
                              hipStream_t stream) {
  const float* q  = (const float*)d_in[0];
  const float* k  = (const float*)d_in[1];
  const float* v  = (const float*)d_in[2];
  const float* Wq = (const float*)d_in[3];
  const float* bq = (const float*)d_in[4];
  const float* Wk = (const float*)d_in[5];
  const float* bk = (const float*)d_in[6];
  const float* Wv = (const float*)d_in[7];
  const float* bv = (const float*)d_in[8];
  const float* Wo = (const float*)d_in[9];
  const float* bo = (const float*)d_in[10];
  float* out = (float*)d_out;

  // workspace layout (~112.1 MiB) with aliasing:
  u16* Wqb = (u16*)d_ws;                 // 4x 1024x1024 bf16 = 8 MiB
  u16* Wkb = Wqb + 1048576;
  u16* Wvb = Wkb + 1048576;
  u16* Wob = Wvb + 1048576;
  u16* Qb  = Wob + 1048576;              // [16384][1024] bf16, 32 MiB
  u16* KT  = Qb  + 16777216;             // [4][1024][4096] bf16, 32 MiB
  u16* VT  = KT  + 16777216;             // [4][1024][4096] bf16, 32 MiB
  u16* KVr = VT  + 16777216;             // [4][1024(d)][1024(l)] bf16, 8 MiB
  float* Ksum = (float*)(KVr + 4194304); // [4][1024] f32
  float* Z    = Ksum + 4096;             // [16384] f32
  u16* Pkv = Qb;   // S2 split-K partials, before Q-proj overwrites
  u16* Pg  = VT;   // G split-K partials, after VT dead
  u16* Gp  = KT;   // G' [4][1024(n)][1024(d)], after KT dead
  // bf16 copies of q,k,v. kb aliases the Qb slot (dead before Pkv/Qb writes);
  // vb,qb live in d_out (only written by the final GEMM, full overwrite).
  u16* kb = Qb;
  u16* vb = (u16*)d_out;                 // bytes [0, 32Mi)
  u16* qb = (u16*)d_out + 16777216;      // bytes [32Mi, 64Mi)

  constexpr size_t LDS = 131072;

  wconv<<<4096, 256, 0, stream>>>(Wq, Wk, Wv, Wo, Wqb);
  qkvconv<<<24576, 256, 0, stream>>>(q, k, v, qb, kb, vb);

  // K,V projections in ONE dispatch (grid z: 0=K with phi, 1=V bias-only).
  dim3 gkv(64, 4, 2);
  gemm_bt<EPI_PHI_BIAS, true, true><<<gkv, 512, LDS, stream>>>(
      kb, Wkb, bk, nullptr, KT, 16384, 1024, 1024, 1024, 1024, 0,
      0, 0, 0, 0, 0, 30, vb, Wvb, bv, VT);

  ksum_rows<<<1024, 256, 0, stream>>>(KT, Ksum);

  // S2: KVr[d,l] = sum_t KT[d,t]*VT[l,t], split-K x4 (z = kslice*4+batch)
  dim3 g2(4, 4, 16);
  gemm_bt<EPI_NONE, false, false><<<g2, 512, LDS, stream>>>(
      KT, VT, nullptr, nullptr, Pkv, 1024, 1024, 1024, 4096, 4096, 1024,
      4194304L, 4194304L, 1048576L, 0, 3, 2, nullptr, nullptr, nullptr, nullptr);
  reduce4<<<2048, 256, 0, stream>>>(Pkv, KVr);

  // Q projection (overwrites partials region — stream-ordered after reduce)
  dim3 g1(64, 4, 1);
  gemm_bt<EPI_PHI_BIAS, false, false><<<g1, 512, LDS, stream>>>(
      qb, Wqb, bq, nullptr, Qb, 16384, 1024, 1024, 1024, 1024, 1024,
      0, 0, 0, 0, 0, 30, nullptr, nullptr, nullptr, nullptr);

  zden<<<4096, 256, 0, stream>>>(Qb, Ksum, Z);

  // G'[n,d] = sum_l Wob[n,l]*KVr[d,l], split-K x4 (K=256/slice); Wo folded in.
  dim3 gg(4, 4, 16);
  gemm_bt<EPI_NONE, false, false><<<gg, 512, LDS, stream>>>(
      Wob, KVr, nullptr, nullptr, Pg, 1024, 1024, 256, 1024, 1024, 1024,
      0L, 1048576L, 1048576L, 0, 3, 2, nullptr, nullptr, nullptr, nullptr);
  reduce4<<<2048, 256, 0, stream>>>(Pg, Gp);

  // final: out[t,n] = Z[t]*(sum_d Qb[t,d]*G'[n,d]) + bo[n], fp32 out
  dim3 gf(16, 4, 4);
  gemm_bt<EPI_ZBIAS_F32, false, false><<<gf, 512, LDS, stream>>>(
      Qb, Gp, bo, Z, out, 4096, 1024, 1024, 1024, 1024, 1024,
      4194304L, 1048576L, 4194304L, 4096L, 3, 30, nullptr, nullptr, nullptr, nullptr);
}

// Round 7
// 454.688 us; speedup vs baseline: 1.0637x; 1.0637x over previous
//
#include <hip/hip_runtime.h>

typedef unsigned short u16;
typedef unsigned int u32;
typedef unsigned long long u64;

typedef __attribute__((ext_vector_type(8))) short short8;   // 8 bf16 = 4 VGPRs
typedef __attribute__((ext_vector_type(4))) float floatx4;  // MFMA accumulator

__device__ __forceinline__ float b2f(u16 h) {
  u32 u = ((u32)h) << 16;
  return __builtin_bit_cast(float, u);
}
__device__ __forceinline__ u16 f2b(float f) {
  u32 u = __builtin_bit_cast(u32, f);
  u32 r = 0x7FFFu + ((u >> 16) & 1u);  // RNE
  return (u16)((u + r) >> 16);
}

// async global->LDS, 16B per lane. LDS dest = wave-uniform base + lane*16.
__device__ __forceinline__ void gl_lds16(const void* g, void* l) {
  __builtin_amdgcn_global_load_lds(
      (__attribute__((address_space(1))) void*)(u64)g,
      (__attribute__((address_space(3))) void*)(u32)(u64)l, 16, 0, 0);
}

// raw workgroup barrier WITHOUT the compiler's vmcnt(0) drain, so
// global_load_lds prefetches stay in flight across it.
__device__ __forceinline__ void wg_barrier() {
  asm volatile("" ::: "memory");
  __builtin_amdgcn_s_barrier();
  asm volatile("" ::: "memory");
}

// trunc-pack 8 fp32 -> 8 bf16 (verified byte order, round-0 kernel)
__device__ __forceinline__ short8 cvt2(const float4& a, const float4& b) {
  union { u32 w[4]; short8 s; } cv;
  const u32* x = (const u32*)&a;
  const u32* y = (const u32*)&b;
  cv.w[0] = __builtin_amdgcn_perm(x[1], x[0], 0x07060302u);
  cv.w[1] = __builtin_amdgcn_perm(x[3], x[2], 0x07060302u);
  cv.w[2] = __builtin_amdgcn_perm(y[1], y[0], 0x07060302u);
  cv.w[3] = __builtin_amdgcn_perm(y[3], y[2], 0x07060302u);
  return cv.s;
}

enum { EPI_PHI_BIAS = 0, EPI_BIAS = 1, EPI_NONE = 2, EPI_ZSCALE = 3,
       EPI_BIAS_F32 = 4, EPI_ZBIAS_F32 = 5 };

// C[m,n] = sum_k A[m,k] * B[n,k]  (K-contiguous). 256x256x64 tile, 8 waves
// (2M x 4N, 128x64 per wave), double-buffered 128KiB LDS, counted-vmcnt
// pipeline (round-4 verified schedule for bf16 A).
//
// A_F32: A is fp32 in global; reg-staged (T14): per thread 16 fp32 regs cover
// 2 chunks (row = tid>>1, chunks {c0,c0+1}, c0=2(tid&1)); k-half kh0 loaded at
// iter top, converted (trunc-pack) + ds_written mid-compute; kh1 loaded mid,
// written at iter end. vmcnt algebra (issue order per iter: [A-kh0 x4, B x4]
// top, [A-kh1 x4] mid):
//   top  vmcnt(12): younger = Akh1(it)4 + new 8 => B(it) landed.
//   mid  vmcnt(4):  younger = B(it+1)4 => Akh0(it+1) regs loaded.
//   end  vmcnt(0):  Akh1(it+1) regs loaded (B landed long before).
//   lgkmcnt(0) after the end ds_writes + barrier => all waves' A writes
//   visible before compute(it+1) (per-wave counters + barrier, round-3 lesson).
// LDS layout per buffer: A[256 rows][8 slots of 16B], phys slot = c ^ (row&7)
// (conflict-free ds_read_b128); B at +32768, same scheme. bf16 staging uses
// linear LDS dest + pre-swizzled global src; fp32 staging writes the swizzled
// slot directly (slot pair = wOff, wOff^16; kh1 = ^64, ^80).
// Block swizzle: XCD-chunked remap, N-tiles of one M-slab adjacent.
// gridDim.y==4, (gx*gy)%8==0 for all launches.
// Split-K: blockIdx.z = kslice*(abmask+1)+batch.
// DUAL: bz selects operand set 1 (A2/B2/bias2/C2, no phi) vs set 0 (phi).
// KSUM (DUAL && TRANS_OUT && phi_on): epilogue accumulates column sums of the
// phi'd tile and atomicAdds into ksum_out[batch*1024+col] (Ksum fused).
template<int EPI, bool A_F32, bool TRANS_OUT, bool DUAL>
__global__ __launch_bounds__(512, 2)
void gemm_bt(const void* __restrict__ Aall, const u16* __restrict__ Ball,
             const float* __restrict__ bias, const float* __restrict__ Zall,
             void* __restrict__ Call,
             int M, int N, int K, int ldA, int ldB, int ldC,
             long sAb, long sBb, long sCb, long sZb, int abmask, int kshift,
             const void* __restrict__ Aall2, const u16* __restrict__ Ball2,
             const float* __restrict__ bias2, void* __restrict__ Call2,
             float* __restrict__ ksum_out)
{
  constexpr int BOFF   = 32768;        // B tile offset within one buffer
  constexpr int STRIDE = 65536;        // one stage buffer (A 32K + B 32K)
  extern __shared__ char smem[];       // 131072 B dynamic

  const int tid  = threadIdx.x;
  const int lane = tid & 63;
  const int wave = tid >> 6;
  const int wm = wave >> 2, wn = wave & 3;   // 2x4 waves, 128x64 each
  const int fl = lane & 15;
  const int q  = lane >> 4;
  const int r4 = q * 4;

  // XCD-chunked block swizzle; consecutive remapped ids iterate the 4 N-tiles
  // of one M-tile.
  const int orig = blockIdx.x + gridDim.x * blockIdx.y;
  const int nwg8 = (gridDim.x * gridDim.y) >> 3;
  const int wsw  = (orig & 7) * nwg8 + (orig >> 3);
  const int bm0 = (wsw >> 2) * 256;          // gridDim.y == 4 in all launches
  const int bn0 = (wsw & 3) * 256;

  const int bz = blockIdx.z;
  const int abz = bz & abmask;
  const int kbase = (bz >> kshift) * K;

  const void* Asel = Aall; const u16* Bsel = Ball;
  const float* biasSel = bias; void* Csel = Call;
  bool phi_on = true;
  if constexpr (DUAL) {
    if (bz) { Asel = Aall2; Bsel = Ball2; biasSel = bias2; Csel = Call2; phi_on = false; }
  }

  const u16* Bp = Bsel + (size_t)abz * sBb + kbase;

  // ---- B staging addresses (global per-lane pre-swizzled; LDS dest linear) --
  const u16* gB[4]; int sLo[4];
  #pragma unroll
  for (int n = 0; n < 4; ++n) {
    int j = n * 512 + tid;
    int row = j >> 3, pc = j & 7, c = pc ^ (row & 7);
    gB[n] = Bp + (size_t)(bn0 + row) * ldB + c * 8;
    sLo[n] = (n * 512 + wave * 64) * 16;
  }

  // ---- fragment LDS byte offsets (within one stage buffer, ks=0) ----
  int aoff[8], boff[4];
  #pragma unroll
  for (int i = 0; i < 8; ++i) {
    int row = wm * 128 + i * 16 + fl;
    aoff[i] = (row * 8 + (q ^ (row & 7))) * 16;
  }
  #pragma unroll
  for (int i = 0; i < 4; ++i) {
    int row = wn * 64 + i * 16 + fl;
    boff[i] = BOFF + (row * 8 + (q ^ (row & 7))) * 16;
  }

  floatx4 zero = {0.f, 0.f, 0.f, 0.f};
  floatx4 acc[8][4];
  #pragma unroll
  for (int i = 0; i < 8; ++i)
    #pragma unroll
    for (int j = 0; j < 4; ++j) acc[i][j] = zero;

  auto stageB = [&](int k0, char* base) {
    #pragma unroll
    for (int n = 0; n < 4; ++n) gl_lds16(gB[n] + k0, base + BOFF + sLo[n]);
  };

  const int NIT = K >> 6;                 // K-tiles of 64

  if constexpr (A_F32) {
    const float* Af = (const float*)Asel + (size_t)abz * sAb + kbase;
    const int arow = tid >> 1, ac0 = (tid & 1) * 2;
    const float* gAf0 = Af + (size_t)(bm0 + arow) * ldA + ac0 * 8;
    const int wOff = (arow * 8 + (ac0 ^ (arow & 7))) * 16;  // kh0 slot A

    float4 Ar[4];                         // 16 VGPRs of in-flight fp32 A
    auto aloadA = [&](int k0) {           // kh0: chunks c0, c0+1
      Ar[0] = *(const float4*)(gAf0 + k0);
      Ar[1] = *(const float4*)(gAf0 + k0 + 4);
      Ar[2] = *(const float4*)(gAf0 + k0 + 8);
      Ar[3] = *(const float4*)(gAf0 + k0 + 12);
    };
    auto aloadB = [&](int k0) {           // kh1: chunks c0+4, c0+5
      Ar[0] = *(const float4*)(gAf0 + k0 + 32);
      Ar[1] = *(const float4*)(gAf0 + k0 + 36);
      Ar[2] = *(const float4*)(gAf0 + k0 + 40);
      Ar[3] = *(const float4*)(gAf0 + k0 + 44);
    };
    auto awriteA = [&](char* base) {
      *(short8*)(base + wOff) = cvt2(Ar[0], Ar[1]);
      *(short8*)(base + (wOff ^ 16)) = cvt2(Ar[2], Ar[3]);
    };
    auto awriteB = [&](char* base) {
      *(short8*)(base + (wOff ^ 64)) = cvt2(Ar[0], Ar[1]);
      *(short8*)(base + (wOff ^ 80)) = cvt2(Ar[2], Ar[3]);
    };

    short8 aF[4], bF[4];
    auto rdB = [&](const char* base, int ks) {
      #pragma unroll
      for (int i = 0; i < 4; ++i) bF[i] = *(const short8*)(base + (boff[i] ^ (ks * 64)));
    };
    auto rdA = [&](const char* base, int mh, int ks) {
      #pragma unroll
      for (int i = 0; i < 4; ++i) aF[i] = *(const short8*)(base + (aoff[mh * 4 + i] ^ (ks * 64)));
    };
    auto mma = [&](int mh) {
      __builtin_amdgcn_s_setprio(1);
      #pragma unroll
      for (int i = 0; i < 4; ++i)
        #pragma unroll
        for (int ni = 0; ni < 4; ++ni)
          acc[mh * 4 + i][ni] =
              __builtin_amdgcn_mfma_f32_16x16x32_bf16(aF[i], bF[ni], acc[mh * 4 + i][ni], 0, 0, 0);
      __builtin_amdgcn_s_setprio(0);
    };

    // prologue: stage tile 0 (A via regs, B via gl_lds)
    aloadA(0); stageB(0, smem);
    asm volatile("s_waitcnt vmcnt(4)" ::: "memory");   // kh0 regs loaded
    awriteA(smem);
    aloadB(0);
    asm volatile("s_waitcnt vmcnt(0)" ::: "memory");   // kh1 regs (+B0) done
    awriteB(smem);
    asm volatile("s_waitcnt lgkmcnt(0)" ::: "memory"); // A0 writes committed

    for (int it = 0; it < NIT; ++it) {
      char* cur = smem + (it & 1) * STRIDE;
      char* nxt = smem + ((it + 1) & 1) * STRIDE;
      const bool pre = (it + 1 < NIT);
      if (pre) {
        aloadA((it + 1) * 64);
        stageB((it + 1) * 64, nxt);
        asm volatile("s_waitcnt vmcnt(12)" ::: "memory");  // B(it) landed
      } else {
        asm volatile("s_waitcnt vmcnt(0)" ::: "memory");
      }
      wg_barrier();                        // all waves: tile-it A+B ready
      // ---- ks = 0 ----
      rdB(cur, 0);
      rdA(cur, 0, 0); mma(0);
      rdA(cur, 1, 0); mma(1);
      if (pre) {
        asm volatile("s_waitcnt vmcnt(4)" ::: "memory");   // kh0(it+1) regs
        awriteA(nxt);
        aloadB((it + 1) * 64);
      }
      // ---- ks = 1 ----
      rdB(cur, 1);
      rdA(cur, 0, 1); mma(0);
      rdA(cur, 1, 1); mma(1);
      if (pre) {
        asm volatile("s_waitcnt vmcnt(0)" ::: "memory");   // kh1(it+1) regs
        awriteB(nxt);
        asm volatile("s_waitcnt lgkmcnt(0)" ::: "memory"); // writes committed
      }
      wg_barrier();                        // WAR + A-write visibility
    }
  } else {
    // round-4 verified bf16 path: A via gl_lds, counted vmcnt(8)
    const u16* Ah = (const u16*)Asel + (size_t)abz * sAb + kbase;
    const u16* gA[4];
    #pragma unroll
    for (int n = 0; n < 4; ++n) {
      int j = n * 512 + tid;
      int row = j >> 3, pc = j & 7, c = pc ^ (row & 7);
      gA[n] = Ah + (size_t)(bm0 + row) * ldA + c * 8;
    }
    auto stage = [&](int k0, char* base) {
      #pragma unroll
      for (int n = 0; n < 4; ++n) gl_lds16(gA[n] + k0, base + sLo[n]);
      stageB(k0, base);
    };
    auto compute = [&](const char* base) {
      #pragma unroll
      for (int ks = 0; ks < 2; ++ks) {
        short8 aF[8], bF[4];
        #pragma unroll
        for (int i = 0; i < 8; ++i) aF[i] = *(const short8*)(base + (aoff[i] ^ (ks * 64)));
        #pragma unroll
        for (int i = 0; i < 4; ++i) bF[i] = *(const short8*)(base + (boff[i] ^ (ks * 64)));
        __builtin_amdgcn_s_setprio(1);
        #pragma unroll
        for (int mi = 0; mi < 8; ++mi)
          #pragma unroll
          for (int ni = 0; ni < 4; ++ni)
            acc[mi][ni] = __builtin_amdgcn_mfma_f32_16x16x32_bf16(aF[mi], bF[ni], acc[mi][ni], 0, 0, 0);
        __builtin_amdgcn_s_setprio(0);
      }
    };
    stage(0, smem);
    for (int it = 0; it < NIT; ++it) {
      if (it + 1 < NIT) {
        stage((it + 1) * 64, smem + ((it + 1) & 1) * STRIDE);
        asm volatile("s_waitcnt vmcnt(8)" ::: "memory");
      } else {
        asm volatile("s_waitcnt vmcnt(0)" ::: "memory");
      }
      wg_barrier();
      compute(smem + (it & 1) * STRIDE);
      if (it + 1 < NIT) wg_barrier();
    }
  }

  if constexpr (!TRANS_OUT) {
    #pragma unroll
    for (int mi = 0; mi < 8; ++mi) {
      #pragma unroll
      for (int ni = 0; ni < 4; ++ni) {
        int col = bn0 + wn * 64 + ni * 16 + fl;
        #pragma unroll
        for (int r = 0; r < 4; ++r) {
          int row = bm0 + wm * 128 + mi * 16 + r4 + r;
          float vv = acc[mi][ni][r];
          if constexpr (EPI == EPI_PHI_BIAS) {
            vv += biasSel[col];
            if (phi_on) vv = __expf(-0.5f * vv * vv);
          }
          if constexpr (EPI == EPI_BIAS || EPI == EPI_BIAS_F32) vv += biasSel[col];
          if constexpr (EPI == EPI_ZSCALE) vv *= Zall[(size_t)abz * sZb + row];
          if constexpr (EPI == EPI_ZBIAS_F32)
            vv = vv * Zall[(size_t)abz * sZb + row] + biasSel[col];
          if constexpr (EPI == EPI_BIAS_F32 || EPI == EPI_ZBIAS_F32)
            ((float*)Csel)[(size_t)bz * sCb + (size_t)row * ldC + col] = vv;
          else
            ((u16*)Csel)[(size_t)bz * sCb + (size_t)row * ldC + col] = f2b(vv);
        }
      }
    }
  } else {
    // transpose through LDS in two 128-t-row passes, then coalesced 16B
    // stores into [4][N][4096]. sT = [256 d][136 t-pad] u16 = 69632 B.
    float ks[4] = {0.f, 0.f, 0.f, 0.f};   // fused Ksum column partials
    __syncthreads();                      // all compute reads done, smem free
    u16* sT = (u16*)smem;
    #pragma unroll
    for (int h = 0; h < 2; ++h) {
      if (wm == h) {
        #pragma unroll
        for (int mi = 0; mi < 8; ++mi) {
          #pragma unroll
          for (int ni = 0; ni < 4; ++ni) {
            int colL = wn * 64 + ni * 16 + fl;
            int row0 = mi * 16 + r4;
            float bcol = biasSel[bn0 + colL];
            ushort4 hh;
            #pragma unroll
            for (int r = 0; r < 4; ++r) {
              float vv = acc[mi][ni][r] + bcol;
              if (phi_on) vv = __expf(-0.5f * vv * vv);
              if constexpr (DUAL) ks[ni] += vv;
              ((u16*)&hh)[r] = f2b(vv);
            }
            *(ushort4*)(sT + colL * 136 + row0) = hh;
          }
        }
      }
      __syncthreads();
      #pragma unroll
      for (int i = 0; i < 8; ++i) {
        int c = i * 512 + tid;            // 4096 x 16B chunks (256 d x 128 t)
        int dloc = c >> 4, t16 = (c & 15) * 8;
        int4 vv = *(const int4*)(sT + dloc * 136 + t16);
        int gd = bn0 + dloc;
        int gt = bm0 + h * 128 + t16;
        int batch = gt >> 12, tt = gt & 4095;
        *(int4*)((u16*)Csel + ((size_t)batch * N + gd) * 4096 + tt) = vv;
      }
      __syncthreads();
    }
    if constexpr (DUAL) {
      if (phi_on) {                       // K-projection blocks: fused Ksum
        #pragma unroll
        for (int ni = 0; ni < 4; ++ni) {
          float s = ks[ni];
          s += __shfl_xor(s, 16, 64);
          s += __shfl_xor(s, 32, 64);
          if (q == 0)
            atomicAdd(ksum_out + ((bm0 >> 12) << 10) + bn0 + wn * 64 + ni * 16 + fl, s);
        }
      }
    }
  }
}

__global__ __launch_bounds__(256)
void wconv(const float* __restrict__ w0, const float* __restrict__ w1,
           const float* __restrict__ w2, const float* __restrict__ w3,
           u16* __restrict__ dst, float* __restrict__ ksum) {
  if (blockIdx.x == 0) {                 // zero Ksum [4][1024] for fused atomics
    float4 z = {0.f, 0.f, 0.f, 0.f};
    #pragma unroll
    for (int i = 0; i < 4; ++i)
      *(float4*)(ksum + threadIdx.x * 16 + i * 4) = z;
  }
  unsigned e = blockIdx.x * 256 + threadIdx.x;
  int mat = e >> 18;
  size_t off = (size_t)(e & 262143) * 4;
  const float* src = mat == 0 ? w0 : mat == 1 ? w1 : mat == 2 ? w2 : w3;
  float4 v = *(const float4*)(src + off);
  ushort4 h;
  h.x = f2b(v.x); h.y = f2b(v.y); h.z = f2b(v.z); h.w = f2b(v.w);
  *(ushort4*)(dst + (size_t)mat * 1048576 + off) = h;
}

// out[i] = round(sum over 4 K-slices of bf16 partials), 4M elems, slice stride 4M
__global__ __launch_bounds__(256)
void reduce4(const u16* __restrict__ P, u16* __restrict__ out) {
  size_t i = ((size_t)blockIdx.x * 256 + threadIdx.x) * 8;
  int4 a = *(const int4*)(P + i);
  int4 b = *(const int4*)(P + i + 4194304);
  int4 c = *(const int4*)(P + i + 8388608);
  int4 d = *(const int4*)(P + i + 12582912);
  const u16* ha = (const u16*)&a; const u16* hb = (const u16*)&b;
  const u16* hc = (const u16*)&c; const u16* hd = (const u16*)&d;
  ushort4 o0, o1;
  #pragma unroll
  for (int j = 0; j < 8; ++j) {
    float s = b2f(ha[j]) + b2f(hb[j]) + b2f(hc[j]) + b2f(hd[j]);
    ((u16*)(j < 4 ? &o0 : &o1))[j & 3] = f2b(s);
  }
  *(ushort4*)(out + i) = o0;
  *(ushort4*)(out + i + 4) = o1;
}

// Z[t] = 1/(Q[t,:]·Ksum[batch,:] + 1e-6); one wave per token
__global__ __launch_bounds__(256)
void zden(const u16* __restrict__ Qb, const float* __restrict__ Ksum,
          float* __restrict__ Z) {
  int lane = threadIdx.x & 63;
  int t = blockIdx.x * 4 + (threadIdx.x >> 6);
  const u16* qp = Qb + (size_t)t * 1024;
  const float* ks = Ksum + (size_t)(t >> 12) * 1024;
  float s = 0.f;
  #pragma unroll
  for (int i = 0; i < 2; ++i) {
    int idx = i * 512 + lane * 8;
    int4 d = *(const int4*)(qp + idx);
    const u16* h = (const u16*)&d;
    float4 k0 = *(const float4*)(ks + idx);
    float4 k1 = *(const float4*)(ks + idx + 4);
    s += b2f(h[0]) * k0.x + b2f(h[1]) * k0.y + b2f(h[2]) * k0.z + b2f(h[3]) * k0.w
       + b2f(h[4]) * k1.x + b2f(h[5]) * k1.y + b2f(h[6]) * k1.z + b2f(h[7]) * k1.w;
  }
  #pragma unroll
  for (int off = 32; off; off >>= 1) s += __shfl_xor(s, off, 64);
  if (lane == 0) Z[t] = 1.0f / (s + 1e-6f);
}

extern "C" void kernel_launch(void* const* d_in, const int* in_sizes, int n_in,
                              void* d_out, int out_size, void* d_ws, size_t ws_size,
                              hipStream_t stream) {
  const float* q  = (const float*)d_in[0];
  const float* k  = (const float*)d_in[1];
  const float* v  = (const float*)d_in[2];
  const float* Wq = (const float*)d_in[3];
  const float* bq = (const float*)d_in[4];
  const float* Wk = (const float*)d_in[5];
  const float* bk = (const float*)d_in[6];
  const float* Wv = (const float*)d_in[7];
  const float* bv = (const float*)d_in[8];
  const float* Wo = (const float*)d_in[9];
  const float* bo = (const float*)d_in[10];
  float* out = (float*)d_out;

  // workspace layout (~112.1 MiB) with aliasing:
  u16* Wqb = (u16*)d_ws;                 // 4x 1024x1024 bf16 = 8 MiB
  u16* Wkb = Wqb + 1048576;
  u16* Wvb = Wkb + 1048576;
  u16* Wob = Wvb + 1048576;
  u16* Qb  = Wob + 1048576;              // [16384][1024] bf16, 32 MiB
  u16* KT  = Qb  + 16777216;             // [4][1024][4096] bf16, 32 MiB
  u16* VT  = KT  + 16777216;             // [4][1024][4096] bf16, 32 MiB
  u16* KVr = VT  + 16777216;             // [4][1024(d)][1024(l)] bf16, 8 MiB
  float* Ksum = (float*)(KVr + 4194304); // [4][1024] f32 (atomically built)
  float* Z    = Ksum + 4096;             // [16384] f32
  u16* Pkv = Qb;   // S2 split-K partials, before Q-proj overwrites
  u16* Pg  = VT;   // G split-K partials, after VT dead
  u16* Gp  = KT;   // G' [4][1024(n)][1024(d)], after KT dead

  constexpr size_t LDS = 131072;

  wconv<<<4096, 256, 0, stream>>>(Wq, Wk, Wv, Wo, Wqb, Ksum);

  // K,V projections in ONE dispatch (grid z: 0=K with phi + fused Ksum,
  // 1=V bias-only). A = fp32 k / v directly (in-kernel conversion).
  dim3 gkv(64, 4, 2);
  gemm_bt<EPI_PHI_BIAS, true, true, true><<<gkv, 512, LDS, stream>>>(
      k, Wkb, bk, nullptr, KT, 16384, 1024, 1024, 1024, 1024, 0,
      0, 0, 0, 0, 0, 30, v, Wvb, bv, VT, Ksum);

  // S2: KVr[d,l] = sum_t KT[d,t]*VT[l,t], split-K x4 (z = kslice*4+batch)
  dim3 g2(4, 4, 16);
  gemm_bt<EPI_NONE, false, false, false><<<g2, 512, LDS, stream>>>(
      KT, VT, nullptr, nullptr, Pkv, 1024, 1024, 1024, 4096, 4096, 1024,
      4194304L, 4194304L, 1048576L, 0, 3, 2, nullptr, nullptr, nullptr, nullptr, nullptr);
  reduce4<<<2048, 256, 0, stream>>>(Pkv, KVr);

  // Q projection from fp32 q (overwrites partials region — stream-ordered)
  dim3 g1(64, 4, 1);
  gemm_bt<EPI_PHI_BIAS, true, false, false><<<g1, 512, LDS, stream>>>(
      q, Wqb, bq, nullptr, Qb, 16384, 1024, 1024, 1024, 1024, 1024,
      0, 0, 0, 0, 0, 30, nullptr, nullptr, nullptr, nullptr, nullptr);

  zden<<<4096, 256, 0, stream>>>(Qb, Ksum, Z);

  // G'[n,d] = sum_l Wob[n,l]*KVr[d,l], split-K x4 (K=256/slice); Wo folded in.
  dim3 gg(4, 4, 16);
  gemm_bt<EPI_NONE, false, false, false><<<gg, 512, LDS, stream>>>(
      Wob, KVr, nullptr, nullptr, Pg, 1024, 1024, 256, 1024, 1024, 1024,
      0L, 1048576L, 1048576L, 0, 3, 2, nullptr, nullptr, nullptr, nullptr, nullptr);
  reduce4<<<2048, 256, 0, stream>>>(Pg, Gp);

  // final: out[t,n] = Z[t]*(sum_d Qb[t,d]*G'[n,d]) + bo[n], fp32 out
  dim3 gf(16, 4, 4);
  gemm_bt<EPI_ZBIAS_F32, false, false, false><<<gf, 512, LDS, stream>>>(
      Qb, Gp, bo, Z, out, 4096, 1024, 1024, 1024, 1024, 1024,
      4194304L, 1048576L, 4194304L, 4096L, 3, 30, nullptr, nullptr, nullptr, nullptr, nullptr);
}

// Round 8
// 441.619 us; speedup vs baseline: 1.0952x; 1.0296x over previous
//
#include <hip/hip_runtime.h>

typedef unsigned short u16;
typedef unsigned int u32;
typedef unsigned long long u64;

typedef __attribute__((ext_vector_type(8))) short short8;   // 8 bf16 = 4 VGPRs
typedef __attribute__((ext_vector_type(4))) float floatx4;  // MFMA accumulator

__device__ __forceinline__ float b2f(u16 h) {
  u32 u = ((u32)h) << 16;
  return __builtin_bit_cast(float, u);
}
__device__ __forceinline__ u16 f2b(float f) {
  u32 u = __builtin_bit_cast(u32, f);
  u32 r = 0x7FFFu + ((u >> 16) & 1u);  // RNE
  return (u16)((u + r) >> 16);
}

// async global->LDS, 16B per lane. LDS dest = wave-uniform base + lane*16.
__device__ __forceinline__ void gl_lds16(const void* g, void* l) {
  __builtin_amdgcn_global_load_lds(
      (__attribute__((address_space(1))) void*)(u64)g,
      (__attribute__((address_space(3))) void*)(u32)(u64)l, 16, 0, 0);
}

// raw workgroup barrier WITHOUT the compiler's vmcnt(0) drain, so
// global_load_lds prefetches stay in flight across it.
__device__ __forceinline__ void wg_barrier() {
  asm volatile("" ::: "memory");
  __builtin_amdgcn_s_barrier();
  asm volatile("" ::: "memory");
}

// trunc-pack 8 fp32 -> 8 bf16 (verified byte order, round-0 kernel)
__device__ __forceinline__ short8 cvt2(const float4& a, const float4& b) {
  union { u32 w[4]; short8 s; } cv;
  const u32* x = (const u32*)&a;
  const u32* y = (const u32*)&b;
  cv.w[0] = __builtin_amdgcn_perm(x[1], x[0], 0x07060302u);
  cv.w[1] = __builtin_amdgcn_perm(x[3], x[2], 0x07060302u);
  cv.w[2] = __builtin_amdgcn_perm(y[1], y[0], 0x07060302u);
  cv.w[3] = __builtin_amdgcn_perm(y[3], y[2], 0x07060302u);
  return cv.s;
}

enum { EPI_PHI_BIAS = 0, EPI_BIAS = 1, EPI_NONE = 2, EPI_ZSCALE = 3,
       EPI_BIAS_F32 = 4, EPI_ZBIAS_F32 = 5 };

// C[m,n] = sum_k A[m,k] * B[n,k]  (K-contiguous). 256x256x64 tile, 8 waves
// (2M x 4N, 128x64 per wave), double-buffered 128KiB LDS, counted-vmcnt
// pipeline (round-4 verified schedule for bf16 A).
//
// A_F32 (round-8 conflict fix): reg-staged with LINEAR physical-slot
// ownership. One LDS row = 128B = one full 32-bank wrap, so a slot's bank
// group depends only on its index-within-row; the only conflict-free wave
// write pattern is linear-in-lane (what gl_lds does in HW). Thread t owns
// phys slots {t, t+512, t+1024, t+1536}: LDS write addr = j*16 (lane-linear,
// conflict-free ds_write_b128); global src = row j>>3, chunk c=(j&7)^(row&7)
// (2x float4 fp32). Two rounds of 2 slots (16 fp32 regs). Wait algebra
// (issue order per iter: [Ar01 x4, B x4] top, [Ar23 x4] mid):
//   mid  vmcnt(4): <=4 outstanding (=B) => Ar01 regs loaded.
//   end  vmcnt(0): Ar23 regs loaded (B landed too); lgkmcnt(0) commits the
//        ds_writes; barrier => all waves see tile-(it+1) A+B complete, so
//        the NEXT iter's top needs no wait at all.
//   Per-wave counters + barrier => cross-wave validity (round-3 lesson).
// WAR: top-of-iter staging targets the buffer last read at iter it-1; the
// end-of-(it-1) barrier separates (reads consumed into MFMAs before barrier).
// LDS layout per buffer: A[256 rows][8 slots of 16B], phys slot = c ^ (row&7)
// (conflict-free ds_read_b128); B at +32768, same scheme. bf16 staging uses
// linear LDS dest + pre-swizzled global src (gl_lds).
// Block swizzle: XCD-chunked remap, N-tiles of one M-slab adjacent.
// gridDim.y==4, (gx*gy)%8==0 for all launches.
// Split-K: blockIdx.z = kslice*(abmask+1)+batch.
// DUAL: bz selects operand set 1 (A2/B2/bias2/C2, no phi) vs set 0 (phi).
// KSUM (DUAL && TRANS_OUT && phi_on): epilogue accumulates column sums of the
// phi'd tile and atomicAdds into ksum_out[batch*1024+col] (Ksum fused).
template<int EPI, bool A_F32, bool TRANS_OUT, bool DUAL>
__global__ __launch_bounds__(512, 2)
void gemm_bt(const void* __restrict__ Aall, const u16* __restrict__ Ball,
             const float* __restrict__ bias, const float* __restrict__ Zall,
             void* __restrict__ Call,
             int M, int N, int K, int ldA, int ldB, int ldC,
             long sAb, long sBb, long sCb, long sZb, int abmask, int kshift,
             const void* __restrict__ Aall2, const u16* __restrict__ Ball2,
             const float* __restrict__ bias2, void* __restrict__ Call2,
             float* __restrict__ ksum_out)
{
  constexpr int BOFF   = 32768;        // B tile offset within one buffer
  constexpr int STRIDE = 65536;        // one stage buffer (A 32K + B 32K)
  extern __shared__ char smem[];       // 131072 B dynamic

  const int tid  = threadIdx.x;
  const int lane = tid & 63;
  const int wave = tid >> 6;
  const int wm = wave >> 2, wn = wave & 3;   // 2x4 waves, 128x64 each
  const int fl = lane & 15;
  const int q  = lane >> 4;
  const int r4 = q * 4;

  // XCD-chunked block swizzle; consecutive remapped ids iterate the 4 N-tiles
  // of one M-tile.
  const int orig = blockIdx.x + gridDim.x * blockIdx.y;
  const int nwg8 = (gridDim.x * gridDim.y) >> 3;
  const int wsw  = (orig & 7) * nwg8 + (orig >> 3);
  const int bm0 = (wsw >> 2) * 256;          // gridDim.y == 4 in all launches
  const int bn0 = (wsw & 3) * 256;

  const int bz = blockIdx.z;
  const int abz = bz & abmask;
  const int kbase = (bz >> kshift) * K;

  const void* Asel = Aall; const u16* Bsel = Ball;
  const float* biasSel = bias; void* Csel = Call;
  bool phi_on = true;
  if constexpr (DUAL) {
    if (bz) { Asel = Aall2; Bsel = Ball2; biasSel = bias2; Csel = Call2; phi_on = false; }
  }

  const u16* Bp = Bsel + (size_t)abz * sBb + kbase;

  // ---- B staging addresses (global per-lane pre-swizzled; LDS dest linear) --
  const u16* gB[4]; int sLo[4];
  #pragma unroll
  for (int n = 0; n < 4; ++n) {
    int j = n * 512 + tid;
    int row = j >> 3, pc = j & 7, c = pc ^ (row & 7);
    gB[n] = Bp + (size_t)(bn0 + row) * ldB + c * 8;
    sLo[n] = (n * 512 + wave * 64) * 16;
  }

  // ---- fragment LDS byte offsets (within one stage buffer, ks=0) ----
  int aoff[8], boff[4];
  #pragma unroll
  for (int i = 0; i < 8; ++i) {
    int row = wm * 128 + i * 16 + fl;
    aoff[i] = (row * 8 + (q ^ (row & 7))) * 16;
  }
  #pragma unroll
  for (int i = 0; i < 4; ++i) {
    int row = wn * 64 + i * 16 + fl;
    boff[i] = BOFF + (row * 8 + (q ^ (row & 7))) * 16;
  }

  floatx4 zero = {0.f, 0.f, 0.f, 0.f};
  floatx4 acc[8][4];
  #pragma unroll
  for (int i = 0; i < 8; ++i)
    #pragma unroll
    for (int j = 0; j < 4; ++j) acc[i][j] = zero;

  auto stageB = [&](int k0, char* base) {
    #pragma unroll
    for (int n = 0; n < 4; ++n) gl_lds16(gB[n] + k0, base + BOFF + sLo[n]);
  };

  const int NIT = K >> 6;                 // K-tiles of 64

  if constexpr (A_F32) {
    const float* Af = (const float*)Asel + (size_t)abz * sAb + kbase;
    // linear phys-slot ownership: slot j = n*512 + tid
    const float* gAs[4]; int wOff[4];
    #pragma unroll
    for (int n = 0; n < 4; ++n) {
      int j = n * 512 + tid;
      int row = j >> 3, c = (j & 7) ^ (row & 7);
      gAs[n] = Af + (size_t)(bm0 + row) * ldA + c * 8;
      wOff[n] = j * 16;
    }

    float4 Ar[4];                         // 16 VGPRs of in-flight fp32 A
    auto aload01 = [&](int k0) {
      Ar[0] = *(const float4*)(gAs[0] + k0);
      Ar[1] = *(const float4*)(gAs[0] + k0 + 4);
      Ar[2] = *(const float4*)(gAs[1] + k0);
      Ar[3] = *(const float4*)(gAs[1] + k0 + 4);
    };
    auto aload23 = [&](int k0) {
      Ar[0] = *(const float4*)(gAs[2] + k0);
      Ar[1] = *(const float4*)(gAs[2] + k0 + 4);
      Ar[2] = *(const float4*)(gAs[3] + k0);
      Ar[3] = *(const float4*)(gAs[3] + k0 + 4);
    };
    auto awrite01 = [&](char* base) {
      *(short8*)(base + wOff[0]) = cvt2(Ar[0], Ar[1]);
      *(short8*)(base + wOff[1]) = cvt2(Ar[2], Ar[3]);
    };
    auto awrite23 = [&](char* base) {
      *(short8*)(base + wOff[2]) = cvt2(Ar[0], Ar[1]);
      *(short8*)(base + wOff[3]) = cvt2(Ar[2], Ar[3]);
    };

    short8 aF[4], bF[4];
    auto rdB = [&](const char* base, int ks) {
      #pragma unroll
      for (int i = 0; i < 4; ++i) bF[i] = *(const short8*)(base + (boff[i] ^ (ks * 64)));
    };
    auto rdA = [&](const char* base, int mh, int ks) {
      #pragma unroll
      for (int i = 0; i < 4; ++i) aF[i] = *(const short8*)(base + (aoff[mh * 4 + i] ^ (ks * 64)));
    };
    auto mma = [&](int mh) {
      __builtin_amdgcn_s_setprio(1);
      #pragma unroll
      for (int i = 0; i < 4; ++i)
        #pragma unroll
        for (int ni = 0; ni < 4; ++ni)
          acc[mh * 4 + i][ni] =
              __builtin_amdgcn_mfma_f32_16x16x32_bf16(aF[i], bF[ni], acc[mh * 4 + i][ni], 0, 0, 0);
      __builtin_amdgcn_s_setprio(0);
    };

    // prologue: stage tile 0 (A via regs, B via gl_lds)
    aload01(0); stageB(0, smem);
    asm volatile("s_waitcnt vmcnt(4)" ::: "memory");   // Ar01 regs loaded
    awrite01(smem);
    aload23(0);
    asm volatile("s_waitcnt vmcnt(0)" ::: "memory");   // Ar23 regs (+B) done
    awrite23(smem);
    asm volatile("s_waitcnt lgkmcnt(0)" ::: "memory"); // A0 writes committed

    for (int it = 0; it < NIT; ++it) {
      const char* cur = smem + (it & 1) * STRIDE;
      char* nxt = smem + ((it + 1) & 1) * STRIDE;
      const bool pre = (it + 1 < NIT);
      if (pre) {
        aload01((it + 1) * 64);
        stageB((it + 1) * 64, nxt);
      }
      wg_barrier();                        // tile it ready (prev-iter end drain)
      // ---- ks = 0 ----
      rdB(cur, 0);
      rdA(cur, 0, 0); mma(0);
      rdA(cur, 1, 0); mma(1);
      if (pre) {
        asm volatile("s_waitcnt vmcnt(4)" ::: "memory");   // Ar01(it+1) regs
        awrite01(nxt);
        aload23((it + 1) * 64);
      }
      // ---- ks = 1 ----
      rdB(cur, 1);
      rdA(cur, 0, 1); mma(0);
      rdA(cur, 1, 1); mma(1);
      if (pre) {
        asm volatile("s_waitcnt vmcnt(0)" ::: "memory");   // Ar23(it+1) regs, B landed
        awrite23(nxt);
        asm volatile("s_waitcnt lgkmcnt(0)" ::: "memory"); // writes committed
      }
      wg_barrier();                        // WAR + tile-(it+1) visibility
    }
  } else {
    // round-4 verified bf16 path: A via gl_lds, counted vmcnt(8)
    const u16* Ah = (const u16*)Asel + (size_t)abz * sAb + kbase;
    const u16* gA[4];
    #pragma unroll
    for (int n = 0; n < 4; ++n) {
      int j = n * 512 + tid;
      int row = j >> 3, pc = j & 7, c = pc ^ (row & 7);
      gA[n] = Ah + (size_t)(bm0 + row) * ldA + c * 8;
    }
    auto stage = [&](int k0, char* base) {
      #pragma unroll
      for (int n = 0; n < 4; ++n) gl_lds16(gA[n] + k0, base + sLo[n]);
      stageB(k0, base);
    };
    auto compute = [&](const char* base) {
      #pragma unroll
      for (int ks = 0; ks < 2; ++ks) {
        short8 aF[8], bF[4];
        #pragma unroll
        for (int i = 0; i < 8; ++i) aF[i] = *(const short8*)(base + (aoff[i] ^ (ks * 64)));
        #pragma unroll
        for (int i = 0; i < 4; ++i) bF[i] = *(const short8*)(base + (boff[i] ^ (ks * 64)));
        __builtin_amdgcn_s_setprio(1);
        #pragma unroll
        for (int mi = 0; mi < 8; ++mi)
          #pragma unroll
          for (int ni = 0; ni < 4; ++ni)
            acc[mi][ni] = __builtin_amdgcn_mfma_f32_16x16x32_bf16(aF[mi], bF[ni], acc[mi][ni], 0, 0, 0);
        __builtin_amdgcn_s_setprio(0);
      }
    };
    stage(0, smem);
    for (int it = 0; it < NIT; ++it) {
      if (it + 1 < NIT) {
        stage((it + 1) * 64, smem + ((it + 1) & 1) * STRIDE);
        asm volatile("s_waitcnt vmcnt(8)" ::: "memory");
      } else {
        asm volatile("s_waitcnt vmcnt(0)" ::: "memory");
      }
      wg_barrier();
      compute(smem + (it & 1) * STRIDE);
      if (it + 1 < NIT) wg_barrier();
    }
  }

  if constexpr (!TRANS_OUT) {
    #pragma unroll
    for (int mi = 0; mi < 8; ++mi) {
      #pragma unroll
      for (int ni = 0; ni < 4; ++ni) {
        int col = bn0 + wn * 64 + ni * 16 + fl;
        #pragma unroll
        for (int r = 0; r < 4; ++r) {
          int row = bm0 + wm * 128 + mi * 16 + r4 + r;
          float vv = acc[mi][ni][r];
          if constexpr (EPI == EPI_PHI_BIAS) {
            vv += biasSel[col];
            if (phi_on) vv = __expf(-0.5f * vv * vv);
          }
          if constexpr (EPI == EPI_BIAS || EPI == EPI_BIAS_F32) vv += biasSel[col];
          if constexpr (EPI == EPI_ZSCALE) vv *= Zall[(size_t)abz * sZb + row];
          if constexpr (EPI == EPI_ZBIAS_F32)
            vv = vv * Zall[(size_t)abz * sZb + row] + biasSel[col];
          if constexpr (EPI == EPI_BIAS_F32 || EPI == EPI_ZBIAS_F32)
            ((float*)Csel)[(size_t)bz * sCb + (size_t)row * ldC + col] = vv;
          else
            ((u16*)Csel)[(size_t)bz * sCb + (size_t)row * ldC + col] = f2b(vv);
        }
      }
    }
  } else {
    // transpose through LDS in two 128-t-row passes, then coalesced 16B
    // stores into [4][N][4096]. sT = [256 d][136 t-pad] u16 = 69632 B.
    float ks[4] = {0.f, 0.f, 0.f, 0.f};   // fused Ksum column partials
    __syncthreads();                      // all compute reads done, smem free
    u16* sT = (u16*)smem;
    #pragma unroll
    for (int h = 0; h < 2; ++h) {
      if (wm == h) {
        #pragma unroll
        for (int mi = 0; mi < 8; ++mi) {
          #pragma unroll
          for (int ni = 0; ni < 4; ++ni) {
            int colL = wn * 64 + ni * 16 + fl;
            int row0 = mi * 16 + r4;
            float bcol = biasSel[bn0 + colL];
            ushort4 hh;
            #pragma unroll
            for (int r = 0; r < 4; ++r) {
              float vv = acc[mi][ni][r] + bcol;
              if (phi_on) vv = __expf(-0.5f * vv * vv);
              if constexpr (DUAL) ks[ni] += vv;
              ((u16*)&hh)[r] = f2b(vv);
            }
            *(ushort4*)(sT + colL * 136 + row0) = hh;
          }
        }
      }
      __syncthreads();
      #pragma unroll
      for (int i = 0; i < 8; ++i) {
        int c = i * 512 + tid;            // 4096 x 16B chunks (256 d x 128 t)
        int dloc = c >> 4, t16 = (c & 15) * 8;
        int4 vv = *(const int4*)(sT + dloc * 136 + t16);
        int gd = bn0 + dloc;
        int gt = bm0 + h * 128 + t16;
        int batch = gt >> 12, tt = gt & 4095;
        *(int4*)((u16*)Csel + ((size_t)batch * N + gd) * 4096 + tt) = vv;
      }
      __syncthreads();
    }
    if constexpr (DUAL) {
      if (phi_on) {                       // K-projection blocks: fused Ksum
        #pragma unroll
        for (int ni = 0; ni < 4; ++ni) {
          float s = ks[ni];
          s += __shfl_xor(s, 16, 64);
          s += __shfl_xor(s, 32, 64);
          if (q == 0)
            atomicAdd(ksum_out + ((bm0 >> 12) << 10) + bn0 + wn * 64 + ni * 16 + fl, s);
        }
      }
    }
  }
}

__global__ __launch_bounds__(256)
void wconv(const float* __restrict__ w0, const float* __restrict__ w1,
           const float* __restrict__ w2, const float* __restrict__ w3,
           u16* __restrict__ dst, float* __restrict__ ksum) {
  if (blockIdx.x == 0) {                 // zero Ksum [4][1024] for fused atomics
    float4 z = {0.f, 0.f, 0.f, 0.f};
    #pragma unroll
    for (int i = 0; i < 4; ++i)
      *(float4*)(ksum + threadIdx.x * 16 + i * 4) = z;
  }
  unsigned e = blockIdx.x * 256 + threadIdx.x;
  int mat = e >> 18;
  size_t off = (size_t)(e & 262143) * 4;
  const float* src = mat == 0 ? w0 : mat == 1 ? w1 : mat == 2 ? w2 : w3;
  float4 v = *(const float4*)(src + off);
  ushort4 h;
  h.x = f2b(v.x); h.y = f2b(v.y); h.z = f2b(v.z); h.w = f2b(v.w);
  *(ushort4*)(dst + (size_t)mat * 1048576 + off) = h;
}

// out[i] = round(sum over 4 K-slices of bf16 partials), 4M elems, slice stride 4M
__global__ __launch_bounds__(256)
void reduce4(const u16* __restrict__ P, u16* __restrict__ out) {
  size_t i = ((size_t)blockIdx.x * 256 + threadIdx.x) * 8;
  int4 a = *(const int4*)(P + i);
  int4 b = *(const int4*)(P + i + 4194304);
  int4 c = *(const int4*)(P + i + 8388608);
  int4 d = *(const int4*)(P + i + 12582912);
  const u16* ha = (const u16*)&a; const u16* hb = (const u16*)&b;
  const u16* hc = (const u16*)&c; const u16* hd = (const u16*)&d;
  ushort4 o0, o1;
  #pragma unroll
  for (int j = 0; j < 8; ++j) {
    float s = b2f(ha[j]) + b2f(hb[j]) + b2f(hc[j]) + b2f(hd[j]);
    ((u16*)(j < 4 ? &o0 : &o1))[j & 3] = f2b(s);
  }
  *(ushort4*)(out + i) = o0;
  *(ushort4*)(out + i + 4) = o1;
}

// Z[t] = 1/(Q[t,:]·Ksum[batch,:] + 1e-6); one wave per token
__global__ __launch_bounds__(256)
void zden(const u16* __restrict__ Qb, const float* __restrict__ Ksum,
          float* __restrict__ Z) {
  int lane = threadIdx.x & 63;
  int t = blockIdx.x * 4 + (threadIdx.x >> 6);
  const u16* qp = Qb + (size_t)t * 1024;
  const float* ks = Ksum + (size_t)(t >> 12) * 1024;
  float s = 0.f;
  #pragma unroll
  for (int i = 0; i < 2; ++i) {
    int idx = i * 512 + lane * 8;
    int4 d = *(const int4*)(qp + idx);
    const u16* h = (const u16*)&d;
    float4 k0 = *(const float4*)(ks + idx);
    float4 k1 = *(const float4*)(ks + idx + 4);
    s += b2f(h[0]) * k0.x + b2f(h[1]) * k0.y + b2f(h[2]) * k0.z + b2f(h[3]) * k0.w
       + b2f(h[4]) * k1.x + b2f(h[5]) * k1.y + b2f(h[6]) * k1.z + b2f(h[7]) * k1.w;
  }
  #pragma unroll
  for (int off = 32; off; off >>= 1) s += __shfl_xor(s, off, 64);
  if (lane == 0) Z[t] = 1.0f / (s + 1e-6f);
}

extern "C" void kernel_launch(void* const* d_in, const int* in_sizes, int n_in,
                              void* d_out, int out_size, void* d_ws, size_t ws_size,
                              hipStream_t stream) {
  const float* q  = (const float*)d_in[0];
  const float* k  = (const float*)d_in[1];
  const float* v  = (const float*)d_in[2];
  const float* Wq = (const float*)d_in[3];
  const float* bq = (const float*)d_in[4];
  const float* Wk = (const float*)d_in[5];
  const float* bk = (const float*)d_in[6];
  const float* Wv = (const float*)d_in[7];
  const float* bv = (const float*)d_in[8];
  const float* Wo = (const float*)d_in[9];
  const float* bo = (const float*)d_in[10];
  float* out = (float*)d_out;

  // workspace layout (~112.1 MiB) with aliasing:
  u16* Wqb = (u16*)d_ws;                 // 4x 1024x1024 bf16 = 8 MiB
  u16* Wkb = Wqb + 1048576;
  u16* Wvb = Wkb + 1048576;
  u16* Wob = Wvb + 1048576;
  u16* Qb  = Wob + 1048576;              // [16384][1024] bf16, 32 MiB
  u16* KT  = Qb  + 16777216;             // [4][1024][4096] bf16, 32 MiB
  u16* VT  = KT  + 16777216;             // [4][1024][4096] bf16, 32 MiB
  u16* KVr = VT  + 16777216;             // [4][1024(d)][1024(l)] bf16, 8 MiB
  float* Ksum = (float*)(KVr + 4194304); // [4][1024] f32 (atomically built)
  float* Z    = Ksum + 4096;             // [16384] f32
  u16* Pkv = Qb;   // S2 split-K partials, before Q-proj overwrites
  u16* Pg  = VT;   // G split-K partials, after VT dead
  u16* Gp  = KT;   // G' [4][1024(n)][1024(d)], after KT dead

  constexpr size_t LDS = 131072;

  wconv<<<4096, 256, 0, stream>>>(Wq, Wk, Wv, Wo, Wqb, Ksum);

  // K,V projections in ONE dispatch (grid z: 0=K with phi + fused Ksum,
  // 1=V bias-only). A = fp32 k / v directly (in-kernel conversion).
  dim3 gkv(64, 4, 2);
  gemm_bt<EPI_PHI_BIAS, true, true, true><<<gkv, 512, LDS, stream>>>(
      k, Wkb, bk, nullptr, KT, 16384, 1024, 1024, 1024, 1024, 0,
      0, 0, 0, 0, 0, 30, v, Wvb, bv, VT, Ksum);

  // S2: KVr[d,l] = sum_t KT[d,t]*VT[l,t], split-K x4 (z = kslice*4+batch)
  dim3 g2(4, 4, 16);
  gemm_bt<EPI_NONE, false, false, false><<<g2, 512, LDS, stream>>>(
      KT, VT, nullptr, nullptr, Pkv, 1024, 1024, 1024, 4096, 4096, 1024,
      4194304L, 4194304L, 1048576L, 0, 3, 2, nullptr, nullptr, nullptr, nullptr, nullptr);
  reduce4<<<2048, 256, 0, stream>>>(Pkv, KVr);

  // Q projection from fp32 q (overwrites partials region — stream-ordered)
  dim3 g1(64, 4, 1);
  gemm_bt<EPI_PHI_BIAS, true, false, false><<<g1, 512, LDS, stream>>>(
      q, Wqb, bq, nullptr, Qb, 16384, 1024, 1024, 1024, 1024, 1024,
      0, 0, 0, 0, 0, 30, nullptr, nullptr, nullptr, nullptr, nullptr);

  zden<<<4096, 256, 0, stream>>>(Qb, Ksum, Z);

  // G'[n,d] = sum_l Wob[n,l]*KVr[d,l], split-K x4 (K=256/slice); Wo folded in.
  dim3 gg(4, 4, 16);
  gemm_bt<EPI_NONE, false, false, false><<<gg, 512, LDS, stream>>>(
      Wob, KVr, nullptr, nullptr, Pg, 1024, 1024, 256, 1024, 1024, 1024,
      0L, 1048576L, 1048576L, 0, 3, 2, nullptr, nullptr, nullptr, nullptr, nullptr);
  reduce4<<<2048, 256, 0, stream>>>(Pg, Gp);

  // final: out[t,n] = Z[t]*(sum_d Qb[t,d]*G'[n,d]) + bo[n], fp32 out
  dim3 gf(16, 4, 4);
  gemm_bt<EPI_ZBIAS_F32, false, false, false><<<gf, 512, LDS, stream>>>(
      Qb, Gp, bo, Z, out, 4096, 1024, 1024, 1024, 1024, 1024,
      4194304L, 1048576L, 4194304L, 4096L, 3, 30, nullptr, nullptr, nullptr, nullptr, nullptr);
}